// Round 6
// baseline (299.908 us; speedup 1.0000x reference)
//
#include <hip/hip_runtime.h>
#include <math.h>

#define TT 256
#define HH 128

__device__ __forceinline__ void enc6(float t, float e[6]) {
  float x = 6.2831853071795864769f * t;
  float a0 = x / 86400.0f, a1 = x / 604800.0f, a2 = x / 2592000.0f;
  e[0] = sinf(a0); e[1] = sinf(a1); e[2] = sinf(a2);
  e[3] = cosf(a0); e[4] = cosf(a1); e[5] = cosf(a2);
}

// blocks 0..2047: embed row; blocks 2048..2055: hper for batch b
__global__ __launch_bounds__(128) void embed_hper_kernel(
    const int* __restrict__ log_seqs, const float* __restrict__ time_seq,
    const float* __restrict__ item_emb, const float* __restrict__ time_proj,
    const float* __restrict__ target_t, const float* __restrict__ pred_W,
    const float* __restrict__ fus_W1, const float* __restrict__ fus_b1,
    float* __restrict__ seqs, float* __restrict__ sc6, float* __restrict__ hp1) {
  int blk = blockIdx.x;
  int tid = threadIdx.x;
  if (blk < 2048) {
    float t = time_seq[blk];
    float e[6]; enc6(t, e);
    int idx = log_seqs[blk];
    const float* tp = time_proj + tid * 6;
    float val = item_emb[(size_t)idx * HH + tid] * 11.313708498984761f; // sqrt(128)
    val += e[0]*tp[0] + e[1]*tp[1] + e[2]*tp[2] + e[3]*tp[3] + e[4]*tp[4] + e[5]*tp[5];
    seqs[(size_t)blk * HH + tid] = (idx != 0) ? val : 0.0f;
    if (tid < 6) sc6[blk * 6 + tid] = e[tid];
  } else {
    int b = blk - 2048;
    __shared__ float te[HH], hp[HH];
    float e[6]; enc6(target_t[b], e);
    const float* tp = time_proj + tid * 6;
    te[tid] = e[0]*tp[0]+e[1]*tp[1]+e[2]*tp[2]+e[3]*tp[3]+e[4]*tp[4]+e[5]*tp[5];
    __syncthreads();
    float u = 0.f;
    const float* pw = pred_W + (size_t)tid * HH;
    for (int d = 0; d < HH; ++d) u += te[d] * pw[d];
    hp[tid] = u;
    __syncthreads();
    float w = fus_b1[tid];
    const float* f1 = fus_W1 + (size_t)tid * 256 + 128;
    for (int d = 0; d < HH; ++d) w += hp[d] * f1[d];
    hp1[b * HH + tid] = w;
  }
}

// which = blk/512: 0=Q (with LN, writes QN too), 1=K(+absK, transposed out), 2=V(+absV).
// 4-row tiles, 1536 blocks x 128 thr.
__global__ __launch_bounds__(128) void qkv_fused(
    const float* __restrict__ S,
    const float* __restrict__ Wq, const float* __restrict__ bq,
    const float* __restrict__ Wk, const float* __restrict__ bk,
    const float* __restrict__ Wv, const float* __restrict__ bv,
    const float* __restrict__ lng, const float* __restrict__ lnb,
    const float* __restrict__ absK, const float* __restrict__ absV,
    float* __restrict__ QN, float* __restrict__ QB,
    float* __restrict__ KT, float* __restrict__ VB) {
  int which = blockIdx.x >> 9;
  int m0 = (blockIdx.x & 511) * 4;
  int n = threadIdx.x;
  __shared__ float At[4][132];
  __shared__ float mu[4], rs[4];
  #pragma unroll
  for (int r = 0; r < 4; ++r) At[r][n] = S[(size_t)(m0 + r) * HH + n];
  __syncthreads();
  if (which == 0) {
    if (n < 32) {
      int r = n >> 3, sg = n & 7;
      float s = 0.f;
      #pragma unroll
      for (int i = 0; i < 16; ++i) s += At[r][sg * 16 + i];
      s += __shfl_xor(s, 1); s += __shfl_xor(s, 2); s += __shfl_xor(s, 4);
      if (sg == 0) mu[r] = s * (1.0f / HH);
    }
    __syncthreads();
    if (n < 32) {
      int r = n >> 3, sg = n & 7;
      float mm = mu[r], s = 0.f;
      #pragma unroll
      for (int i = 0; i < 16; ++i) { float d = At[r][sg*16+i] - mm; s += d * d; }
      s += __shfl_xor(s, 1); s += __shfl_xor(s, 2); s += __shfl_xor(s, 4);
      if (sg == 0) rs[r] = rsqrtf(s * (1.0f / HH) + 1e-8f);
    }
    __syncthreads();
    float gg = lng[n], bb = lnb[n];
    #pragma unroll
    for (int r = 0; r < 4; ++r) {
      float v = (At[r][n] - mu[r]) * rs[r] * gg + bb;
      At[r][n] = v;
      QN[(size_t)(m0 + r) * HH + n] = v;
    }
    __syncthreads();
  }
  const float* W    = which == 0 ? Wq : which == 1 ? Wk : Wv;
  const float* bias = which == 0 ? bq : which == 1 ? bk : bv;
  const float* addP = which == 1 ? absK : which == 2 ? absV : nullptr;
  float* dst        = which == 0 ? QB : which == 1 ? KT : VB;
  float acc[4] = {0.f, 0.f, 0.f, 0.f};
  const float* wr = W + (size_t)n * HH;
  for (int d = 0; d < HH; d += 4) {
    float4 w = *(const float4*)(wr + d);
    #pragma unroll
    for (int r = 0; r < 4; ++r) {
      float4 a = *(const float4*)(&At[r][d]);
      acc[r] = fmaf(a.x, w.x, fmaf(a.y, w.y, fmaf(a.z, w.z, fmaf(a.w, w.w, acc[r]))));
    }
  }
  float bn = bias[n];
  #pragma unroll
  for (int r = 0; r < 4; ++r) {
    int m = m0 + r;
    float v = acc[r] + bn;
    if (addP) v += addP[(size_t)(m & 255) * HH + n];
    if (which == 1) {
      // KT[((b*2+h)*64 + d)*256 + t]
      int bb2 = m >> 8, t = m & 255, hh2 = n >> 6, dd = n & 63;
      dst[(((size_t)(bb2 * 2 + hh2) * 64) + dd) * 256 + t] = v;
    } else {
      dst[(size_t)m * HH + n] = v;
    }
  }
}

// Fully-fused attention: PK (q . tKe[i]) in LDS, scores, softmax, PV.
// grid 1024 (XCD-swizzled): bh(16) x qtile(64, 4q each); 256 thr.
__global__ __launch_bounds__(256) void attn_fused(
    const float* __restrict__ QB, const float* __restrict__ KT,
    const float* __restrict__ VB, const float* __restrict__ QN,
    const int* __restrict__ log_seqs, const int* __restrict__ tmat,
    const float* __restrict__ sc6, const float* __restrict__ tKe,
    const float* __restrict__ tVe, const float* __restrict__ lambdas,
    float* __restrict__ out) {
  int blk = blockIdx.x;
  blk = (blk & 7) * 128 + (blk >> 3);   // bijective (1024 = 8*128)
  int qt = blk & 63;
  int h = (blk >> 6) & 1;
  int b = blk >> 7;
  int q0 = qt << 2;
  int hoff = h << 6;
  int tid = threadIdx.x;
  int w = tid >> 6, lane = tid & 63;

  __shared__ float Qs[4][64];
  __shared__ float PKs[4][260];
  __shared__ float sk6T[6][256];
  __shared__ float sq6v[4][6];
  __shared__ unsigned short tmq[4][256];
  __shared__ unsigned char kmask[256];
  __shared__ float Pp[4][256];
  __shared__ float part[4][4][64];
  __shared__ float redm[4];

  { int q = tid >> 6, d = tid & 63;
    Qs[q][d] = QB[((size_t)(b * TT + q0 + q)) * HH + hoff + d]; }
  for (int idx = tid; idx < 1536; idx += 256) {
    int kk = idx / 6, cc = idx - kk * 6;
    sk6T[cc][kk] = sc6[(size_t)b * 1536 + idx];
  }
  if (tid < 24) {
    int q = tid / 6, cc = tid - q * 6;
    sq6v[q][cc] = sc6[((size_t)(b * TT + q0 + q)) * 6 + cc];
  }
  #pragma unroll
  for (int t = 0; t < 4; ++t) {
    int idx = tid + (t << 8);
    int qq = idx >> 8, kk = idx & 255;
    tmq[qq][kk] = (unsigned short)tmat[((size_t)(b * TT + q0 + qq)) * TT + kk];
  }
  kmask[tid] = (log_seqs[b * TT + tid] == 0) ? 1 : 0;
  __syncthreads();

  // Phase A: PK[q][i] = 0.125 * dot(Qs[q], tKe[i])
  for (int i = tid; i < 257; i += 256) {
    const float* tp = tKe + (size_t)i * HH + hoff;
    float a0 = 0.f, a1 = 0.f, a2 = 0.f, a3 = 0.f;
    #pragma unroll
    for (int d = 0; d < 64; d += 4) {
      float4 t4 = *(const float4*)(tp + d);
      float4 v0 = *(const float4*)(&Qs[0][d]);
      float4 v1 = *(const float4*)(&Qs[1][d]);
      float4 v2 = *(const float4*)(&Qs[2][d]);
      float4 v3 = *(const float4*)(&Qs[3][d]);
      a0 = fmaf(v0.x,t4.x,fmaf(v0.y,t4.y,fmaf(v0.z,t4.z,fmaf(v0.w,t4.w,a0))));
      a1 = fmaf(v1.x,t4.x,fmaf(v1.y,t4.y,fmaf(v1.z,t4.z,fmaf(v1.w,t4.w,a1))));
      a2 = fmaf(v2.x,t4.x,fmaf(v2.y,t4.y,fmaf(v2.z,t4.z,fmaf(v2.w,t4.w,a2))));
      a3 = fmaf(v3.x,t4.x,fmaf(v3.y,t4.y,fmaf(v3.z,t4.z,fmaf(v3.w,t4.w,a3))));
    }
    PKs[0][i] = a0 * 0.125f; PKs[1][i] = a1 * 0.125f;
    PKs[2][i] = a2 * 0.125f; PKs[3][i] = a3 * 0.125f;
  }
  __syncthreads();

  // Phase B: scores. thread = k; coalesced KT reads.
  int k = tid;
  {
    float d0 = 0.f, d1 = 0.f, d2 = 0.f, d3 = 0.f;
    if (k <= q0 + 3) {   // beyond causal frontier scores are -1e9 regardless
      const float* ktc = KT + ((size_t)((b * 2 + h) * 64)) * 256 + k;
      #pragma unroll
      for (int d4 = 0; d4 < 16; ++d4) {
        float4 qa = *(const float4*)(&Qs[0][d4 << 2]);
        float4 qb = *(const float4*)(&Qs[1][d4 << 2]);
        float4 qc = *(const float4*)(&Qs[2][d4 << 2]);
        float4 qd = *(const float4*)(&Qs[3][d4 << 2]);
        float v0 = ktc[(size_t)((d4 << 2) + 0) * 256];
        float v1 = ktc[(size_t)((d4 << 2) + 1) * 256];
        float v2 = ktc[(size_t)((d4 << 2) + 2) * 256];
        float v3 = ktc[(size_t)((d4 << 2) + 3) * 256];
        d0 = fmaf(qa.x, v0, fmaf(qa.y, v1, fmaf(qa.z, v2, fmaf(qa.w, v3, d0))));
        d1 = fmaf(qb.x, v0, fmaf(qb.y, v1, fmaf(qb.z, v2, fmaf(qb.w, v3, d1))));
        d2 = fmaf(qc.x, v0, fmaf(qc.y, v1, fmaf(qc.z, v2, fmaf(qc.w, v3, d2))));
        d3 = fmaf(qd.x, v0, fmaf(qd.y, v1, fmaf(qd.z, v2, fmaf(qd.w, v3, d3))));
      }
    }
    float dq[4] = {d0, d1, d2, d3};
    float l0 = lambdas[0], l1 = lambdas[1], l2 = lambdas[2];
    float c0 = sk6T[0][k], c1 = sk6T[1][k], c2 = sk6T[2][k],
          c3 = sk6T[3][k], c4 = sk6T[4][k], c5 = sk6T[5][k];
    int km = kmask[k];
    #pragma unroll
    for (int qq = 0; qq < 4; ++qq) {
      int qg = q0 + qq;
      float sv = -1e9f;
      if (k <= qg && !km) {
        float pb = l0 * (sq6v[qq][0] * c0 + sq6v[qq][3] * c3)
                 + l1 * (sq6v[qq][1] * c1 + sq6v[qq][4] * c4)
                 + l2 * (sq6v[qq][2] * c2 + sq6v[qq][5] * c5);
        sv = fmaf(dq[qq], 0.125f, PKs[qq][tmq[qq][k]] + pb);
      }
      Pp[qq][k] = sv;
    }
  }
  __syncthreads();

  // Phase C: softmax — wave w owns q-row w.
  {
    float s4[4];
    #pragma unroll
    for (int j = 0; j < 4; ++j) s4[j] = Pp[w][lane + (j << 6)];
    float mx = fmaxf(fmaxf(s4[0], s4[1]), fmaxf(s4[2], s4[3]));
    #pragma unroll
    for (int o = 32; o > 0; o >>= 1) mx = fmaxf(mx, __shfl_xor(mx, o));
    bool full = (mx < -5e8f);   // fully-masked row -> uniform attention (ref)
    float p[4], sum = 0.f;
    #pragma unroll
    for (int j = 0; j < 4; ++j) { p[j] = full ? 1.0f : __expf(s4[j] - mx); sum += p[j]; }
    #pragma unroll
    for (int o = 32; o > 0; o >>= 1) sum += __shfl_xor(sum, o);
    float inv = 1.0f / sum;
    #pragma unroll
    for (int j = 0; j < 4; ++j) Pp[w][lane + (j << 6)] = p[j] * inv;
    if (lane == 0) redm[w] = mx;
  }
  __syncthreads();

  bool anyfull = (redm[0] < -5e8f) || (redm[1] < -5e8f) ||
                 (redm[2] < -5e8f) || (redm[3] < -5e8f);
  int kend = anyfull ? 256 : (q0 + 4);

  // Phase D: PV. wave w takes k = w, w+4, ...; lane = d. V row shared by 4 q.
  float o0 = 0.f, o1 = 0.f, o2 = 0.f, o3 = 0.f;
  const float* vbase = VB + ((size_t)(b * TT)) * HH + hoff + lane;
  const float* tvb   = tVe + hoff + lane;
  for (int kk = w; kk < kend; kk += 4) {
    float v = vbase[(size_t)kk * HH];
    float pA = Pp[0][kk], pB = Pp[1][kk], pC = Pp[2][kk], pD = Pp[3][kk];
    float tA = tvb[(size_t)tmq[0][kk] * HH];
    float tB = tvb[(size_t)tmq[1][kk] * HH];
    float tC = tvb[(size_t)tmq[2][kk] * HH];
    float tD = tvb[(size_t)tmq[3][kk] * HH];
    o0 = fmaf(pA, v + tA, o0);
    o1 = fmaf(pB, v + tB, o1);
    o2 = fmaf(pC, v + tC, o2);
    o3 = fmaf(pD, v + tD, o3);
  }
  part[w][0][lane] = o0;
  part[w][1][lane] = o1;
  part[w][2][lane] = o2;
  part[w][3][lane] = o3;
  __syncthreads();
  { int qq = tid >> 6, d = tid & 63;
    float o = part[0][qq][d] + part[1][qq][d] + part[2][qq][d] + part[3][qq][d];
    size_t ob = ((size_t)(b * TT + q0 + qq)) * HH + hoff + d;
    out[ob] = QN[ob] + o; }
}

// LN + relu(x@W1^T+b1)@W2^T + b2 + x, keep-mask. 4-row tiles.
__global__ __launch_bounds__(128) void ffn_fused(
    const float* __restrict__ S, const float* __restrict__ W1, const float* __restrict__ b1,
    const float* __restrict__ W2, const float* __restrict__ b2,
    const float* __restrict__ lng, const float* __restrict__ lnb,
    const int* __restrict__ log_seqs, float* __restrict__ outS) {
  int m0 = blockIdx.x * 4;
  int n = threadIdx.x;
  __shared__ float Xt[4][132];
  __shared__ float Ht[4][132];
  __shared__ float mu[4], rs[4];
  #pragma unroll
  for (int r = 0; r < 4; ++r) Xt[r][n] = S[(size_t)(m0 + r) * HH + n];
  __syncthreads();
  if (n < 32) {
    int r = n >> 3, sg = n & 7;
    float s = 0.f;
    #pragma unroll
    for (int i = 0; i < 16; ++i) s += Xt[r][sg * 16 + i];
    s += __shfl_xor(s, 1); s += __shfl_xor(s, 2); s += __shfl_xor(s, 4);
    if (sg == 0) mu[r] = s * (1.0f / HH);
  }
  __syncthreads();
  if (n < 32) {
    int r = n >> 3, sg = n & 7;
    float mm = mu[r], s = 0.f;
    #pragma unroll
    for (int i = 0; i < 16; ++i) { float d = Xt[r][sg*16+i] - mm; s += d * d; }
    s += __shfl_xor(s, 1); s += __shfl_xor(s, 2); s += __shfl_xor(s, 4);
    if (sg == 0) rs[r] = rsqrtf(s * (1.0f / HH) + 1e-8f);
  }
  __syncthreads();
  float gg = lng[n], bb = lnb[n];
  #pragma unroll
  for (int r = 0; r < 4; ++r) Xt[r][n] = (Xt[r][n] - mu[r]) * rs[r] * gg + bb;
  __syncthreads();
  float acc[4] = {0.f, 0.f, 0.f, 0.f};
  const float* wr = W1 + (size_t)n * HH;
  for (int d = 0; d < HH; d += 4) {
    float4 w = *(const float4*)(wr + d);
    #pragma unroll
    for (int r = 0; r < 4; ++r) {
      float4 a = *(const float4*)(&Xt[r][d]);
      acc[r] = fmaf(a.x, w.x, fmaf(a.y, w.y, fmaf(a.z, w.z, fmaf(a.w, w.w, acc[r]))));
    }
  }
  float b1n = b1[n];
  #pragma unroll
  for (int r = 0; r < 4; ++r) Ht[r][n] = fmaxf(acc[r] + b1n, 0.f);
  __syncthreads();
  float acc2[4] = {0.f, 0.f, 0.f, 0.f};
  wr = W2 + (size_t)n * HH;
  for (int d = 0; d < HH; d += 4) {
    float4 w = *(const float4*)(wr + d);
    #pragma unroll
    for (int r = 0; r < 4; ++r) {
      float4 a = *(const float4*)(&Ht[r][d]);
      acc2[r] = fmaf(a.x, w.x, fmaf(a.y, w.y, fmaf(a.z, w.z, fmaf(a.w, w.w, acc2[r]))));
    }
  }
  float b2n = b2[n];
  #pragma unroll
  for (int r = 0; r < 4; ++r) {
    int mrow = m0 + r;
    float v = acc2[r] + b2n + Xt[r][n];
    if (log_seqs[mrow] == 0) v = 0.f;
    outS[(size_t)mrow * HH + n] = v;
  }
}

// last LN + gelu(L@fus_W1[:, :128]^T + hp1) @ fus_W2^T + fus_b2 -> logits. 4-row tiles.
__global__ __launch_bounds__(128) void final_fused(
    const float* __restrict__ S, const float* __restrict__ lng, const float* __restrict__ lnb,
    const float* __restrict__ fus_W1, const float* __restrict__ HP1,
    const float* __restrict__ fus_W2, const float* __restrict__ fus_b2,
    const float* __restrict__ item_emb, const int* __restrict__ pos,
    const int* __restrict__ neg, float* __restrict__ out) {
  int m0 = blockIdx.x * 4;
  int bidx = m0 >> 8;
  int n = threadIdx.x;
  __shared__ float Xt[4][132];
  __shared__ float Ht[4][132];
  __shared__ float Ft[4][132];
  __shared__ float mu[4], rs[4];
  #pragma unroll
  for (int r = 0; r < 4; ++r) Xt[r][n] = S[(size_t)(m0 + r) * HH + n];
  __syncthreads();
  if (n < 32) {
    int r = n >> 3, sg = n & 7;
    float s = 0.f;
    #pragma unroll
    for (int i = 0; i < 16; ++i) s += Xt[r][sg * 16 + i];
    s += __shfl_xor(s, 1); s += __shfl_xor(s, 2); s += __shfl_xor(s, 4);
    if (sg == 0) mu[r] = s * (1.0f / HH);
  }
  __syncthreads();
  if (n < 32) {
    int r = n >> 3, sg = n & 7;
    float mm = mu[r], s = 0.f;
    #pragma unroll
    for (int i = 0; i < 16; ++i) { float d = Xt[r][sg*16+i] - mm; s += d * d; }
    s += __shfl_xor(s, 1); s += __shfl_xor(s, 2); s += __shfl_xor(s, 4);
    if (sg == 0) rs[r] = rsqrtf(s * (1.0f / HH) + 1e-8f);
  }
  __syncthreads();
  float gg = lng[n], bb = lnb[n];
  #pragma unroll
  for (int r = 0; r < 4; ++r) Xt[r][n] = (Xt[r][n] - mu[r]) * rs[r] * gg + bb;
  __syncthreads();
  float acc[4] = {0.f, 0.f, 0.f, 0.f};
  const float* wr = fus_W1 + (size_t)n * 256;
  for (int d = 0; d < HH; d += 4) {
    float4 w = *(const float4*)(wr + d);
    #pragma unroll
    for (int r = 0; r < 4; ++r) {
      float4 a = *(const float4*)(&Xt[r][d]);
      acc[r] = fmaf(a.x, w.x, fmaf(a.y, w.y, fmaf(a.z, w.z, fmaf(a.w, w.w, acc[r]))));
    }
  }
  float hp = HP1[bidx * HH + n];
  #pragma unroll
  for (int r = 0; r < 4; ++r) {
    float v = acc[r] + hp;
    Ht[r][n] = 0.5f * v * (1.0f + erff(v * 0.70710678118654752f));
  }
  __syncthreads();
  float acc2[4] = {0.f, 0.f, 0.f, 0.f};
  wr = fus_W2 + (size_t)n * HH;
  for (int d = 0; d < HH; d += 4) {
    float4 w = *(const float4*)(wr + d);
    #pragma unroll
    for (int r = 0; r < 4; ++r) {
      float4 a = *(const float4*)(&Ht[r][d]);
      acc2[r] = fmaf(a.x, w.x, fmaf(a.y, w.y, fmaf(a.z, w.z, fmaf(a.w, w.w, acc2[r]))));
    }
  }
  float b2n = fus_b2[n];
  #pragma unroll
  for (int r = 0; r < 4; ++r) Ft[r][n] = acc2[r] + b2n;
  __syncthreads();
  if (n < 64) {
    int task = n >> 3;     // 0..7: r = task&3, which = task>>2
    int sg = n & 7;
    int r = task & 3;
    int w = task >> 2;
    int mrow = m0 + r;
    int idx = (w == 0) ? pos[mrow] : neg[mrow];
    const float* ie = item_emb + (size_t)idx * HH;
    float s = 0.f;
    #pragma unroll
    for (int i = 0; i < 16; ++i) s += Ft[r][sg * 16 + i] * ie[sg * 16 + i];
    s += __shfl_xor(s, 1); s += __shfl_xor(s, 2); s += __shfl_xor(s, 4);
    if (sg == 0) out[w * 2048 + mrow] = s;
  }
}

extern "C" void kernel_launch(void* const* d_in, const int* in_sizes, int n_in,
                              void* d_out, int out_size, void* d_ws, size_t ws_size,
                              hipStream_t stream) {
  const int*   log_seqs   = (const int*)d_in[0];
  const int*   tmat       = (const int*)d_in[1];
  const float* time_seq   = (const float*)d_in[2];
  const int*   pos_seqs   = (const int*)d_in[3];
  const int*   neg_seqs   = (const int*)d_in[4];
  const float* target_t   = (const float*)d_in[5];
  const float* item_emb   = (const float*)d_in[6];
  const float* abs_pos_K  = (const float*)d_in[7];
  const float* abs_pos_V  = (const float*)d_in[8];
  const float* time_K_emb = (const float*)d_in[9];
  const float* time_V_emb = (const float*)d_in[10];
  const float* Wq = (const float*)d_in[11];
  const float* bq = (const float*)d_in[12];
  const float* Wk = (const float*)d_in[13];
  const float* bk = (const float*)d_in[14];
  const float* Wv = (const float*)d_in[15];
  const float* bv = (const float*)d_in[16];
  const float* attn_ln_g = (const float*)d_in[17];
  const float* attn_ln_b = (const float*)d_in[18];
  const float* fwd_ln_g = (const float*)d_in[19];
  const float* fwd_ln_b = (const float*)d_in[20];
  const float* w1 = (const float*)d_in[21];
  const float* b1 = (const float*)d_in[22];
  const float* w2 = (const float*)d_in[23];
  const float* b2 = (const float*)d_in[24];
  const float* last_ln_g = (const float*)d_in[25];
  const float* last_ln_b = (const float*)d_in[26];
  const float* time_proj = (const float*)d_in[27];
  const float* lambdas = (const float*)d_in[28];
  const float* pred_W = (const float*)d_in[29];
  const float* fus_W1 = (const float*)d_in[30];
  const float* fus_b1 = (const float*)d_in[31];
  const float* fus_W2 = (const float*)d_in[32];
  const float* fus_b2 = (const float*)d_in[33];
  (void)in_sizes; (void)n_in; (void)out_size; (void)ws_size;

  float* out = (float*)d_out;
  float* ws = (float*)d_ws;
  const int M = 8 * TT;  // 2048
  float* SC6  = ws;                 // M*6
  float* SEQS = SC6 + M * 6;
  float* QN   = SEQS + M * HH;
  float* QB   = QN + M * HH;
  float* KT   = QB + M * HH;        // [b][h][d][t]
  float* VB   = KT + M * HH;
  float* HP1  = VB + M * HH;        // 8*128

  embed_hper_kernel<<<2056, 128, 0, stream>>>(log_seqs, time_seq, item_emb, time_proj,
                                              target_t, pred_W, fus_W1, fus_b1,
                                              SEQS, SC6, HP1);
  for (int l = 0; l < 2; ++l) {
    const size_t wo = (size_t)l * HH * HH;
    const size_t bo = (size_t)l * HH;
    qkv_fused<<<1536, 128, 0, stream>>>(SEQS, Wq + wo, bq + bo, Wk + wo, bk + bo,
                                        Wv + wo, bv + bo, attn_ln_g + bo, attn_ln_b + bo,
                                        abs_pos_K, abs_pos_V, QN, QB, KT, VB);
    attn_fused<<<1024, 256, 0, stream>>>(QB, KT, VB, QN, log_seqs, tmat, SC6,
                                         time_K_emb, time_V_emb, lambdas, SEQS);
    ffn_fused<<<512, 128, 0, stream>>>(SEQS, w1 + wo, b1 + bo, w2 + wo, b2 + bo,
                                       fwd_ln_g + bo, fwd_ln_b + bo, log_seqs, SEQS);
  }
  final_fused<<<512, 128, 0, stream>>>(SEQS, last_ln_g, last_ln_b, fus_W1, HP1,
                                       fus_W2, fus_b2, item_emb, pos_seqs, neg_seqs, out);
}